// Round 4
// baseline (560.787 us; speedup 1.0000x reference)
//
#include <hip/hip_runtime.h>

// L2LGD2: learned-optimizer update step (GRUCell hid=8 + Dense(1) per row).
//
// R7: kill the scratch-spill floor + true software pipeline.
// Post-mortem R3/R5/R6: all three structurally different kernels hit ~195-210us.
// Shared defect: the PIN + memory-clobber trick does NOT force residency — the
// allocator may still SPILL pinned values to scratch and reload per iteration
// (R6: 69 pinned weight VGPRs, only 60 allocated -> impossible without spills).
// occ% x VGPR ~= const across rounds shows the allocator trading spills for
// occupancy under the (256,4)=128-reg budget, losing both ways.
// Fixes:
//  (a) __launch_bounds__(256, 2): 256-VGPR budget. All ~69 weight regs +
//      pipeline slots become genuinely resident; scratch traffic -> 0.
//  (b) Software pipeline: per loop iteration, issue the NEXT pair's 4 loads
//      first, then compute the current two bodies (~1600 cyc) — HBM latency
//      (~900 cyc) is hidden inside a single wave, so even ~2 waves/SIMD
//      (the occupancy cost of (a)) keeps the VALU saturated.
// Body math is bit-identical to R6 (packed v_pk_fma_f32 + DPP quad_perm),
// so absmax is unchanged.

typedef float f32x2 __attribute__((ext_vector_type(2)));

#define PIN(x) asm volatile("" : "+v"(x))

// DPP cross-lane within the 4-lane quad (row group). ctrl is quad_perm code.
#define QP(x, ctrl) __int_as_float(__builtin_amdgcn_mov_dpp(__float_as_int(x), (ctrl), 0xF, 0xF, false))
#define QP_B0 0x00   // broadcast quad lane 0
#define QP_B1 0x55
#define QP_B2 0xAA
#define QP_B3 0xFF
#define QP_X1 0xB1   // [1,0,3,2] xor 1
#define QP_X2 0x4E   // [2,3,0,1] xor 2

// d += a * broadcast(b.lo)   [all operands f32x2 register pairs]
#define PK_FMA_BLO(d, a, bp) \
    asm("v_pk_fma_f32 %0, %1, %2, %0 op_sel:[0,0,0] op_sel_hi:[1,0,1]" \
        : "+v"(d) : "v"(a), "v"(bp))
// d += a * broadcast(b.hi)
#define PK_FMA_BHI(d, a, bp) \
    asm("v_pk_fma_f32 %0, %1, %2, %0 op_sel:[0,1,0] op_sel_hi:[1,1,1]" \
        : "+v"(d) : "v"(a), "v"(bp))
// d = a * broadcast(b.lo) + c   (fresh dest)
#define PK_FMA3_BLO(d, a, bp, c) \
    asm("v_pk_fma_f32 %0, %1, %2, %3 op_sel:[0,0,0] op_sel_hi:[1,0,1]" \
        : "=v"(d) : "v"(a), "v"(bp), "v"(c))
// d = a * broadcast(b.lo)   (fresh dest)
#define PK_MUL_BLO(d, a, bp) \
    asm("v_pk_mul_f32 %0, %1, %2 op_sel:[0,0] op_sel_hi:[1,0]" \
        : "=v"(d) : "v"(a), "v"(bp))

__global__ __launch_bounds__(256, 2) void gru_l2l_kernel(
    const float* __restrict__ hp, const float* __restrict__ gp,
    const float* __restrict__ Wi_r, const float* __restrict__ Wh_r, const float* __restrict__ bh_r,
    const float* __restrict__ Wi_z, const float* __restrict__ Wh_z, const float* __restrict__ bh_z,
    const float* __restrict__ Wi_n, const float* __restrict__ Wh_n, const float* __restrict__ bh_n,
    const float* __restrict__ Wm, const float* __restrict__ bm,
    float* __restrict__ out, int nrows)
{
    const int npairs = nrows << 2;               // h as float2 elements
    const int tid    = blockIdx.x * blockDim.x + threadIdx.x;
    const int stride = blockDim.x * gridDim.x;   // multiple of 4 -> m loop-invariant
    const int m      = tid & 3;                  // column pair owned: {2m, 2m+1}
    const int c0     = m << 1;

    const float L2E = 1.44269504088896341f;      // log2(e)

    // Packed per-lane weights: columns (c0, c0+1). Wi_* [2,8], Wh_* [8,8] row-major.
    // r/z weights+biases pre-scaled by log2e: sigmoid(x) = rcp(1 + exp2(-x*log2e)).
    f32x2 wir0 = { Wi_r[c0] * L2E,     Wi_r[c0 + 1] * L2E };
    f32x2 wir1 = { Wi_r[8 + c0] * L2E, Wi_r[8 + c0 + 1] * L2E };
    f32x2 wiz0 = { Wi_z[c0] * L2E,     Wi_z[c0 + 1] * L2E };
    f32x2 wiz1 = { Wi_z[8 + c0] * L2E, Wi_z[8 + c0 + 1] * L2E };
    f32x2 win0 = { Wi_n[c0],           Wi_n[c0 + 1] };
    f32x2 win1 = { Wi_n[8 + c0],       Wi_n[8 + c0 + 1] };
    f32x2 whr[8], whz[8], whn[8];
#pragma unroll
    for (int k = 0; k < 8; ++k) {
        whr[k] = (f32x2){ Wh_r[k * 8 + c0] * L2E, Wh_r[k * 8 + c0 + 1] * L2E };
        whz[k] = (f32x2){ Wh_z[k * 8 + c0] * L2E, Wh_z[k * 8 + c0 + 1] * L2E };
        whn[k] = (f32x2){ Wh_n[k * 8 + c0],       Wh_n[k * 8 + c0 + 1] };
    }
    f32x2 br = { bh_r[c0] * L2E, bh_r[c0 + 1] * L2E };
    f32x2 bz = { bh_z[c0] * L2E, bh_z[c0 + 1] * L2E };
    f32x2 bn = { bh_n[c0],       bh_n[c0 + 1] };
    float wmx  = Wm[c0], wmy = Wm[c0 + 1];
    float bmv2 = bm[0] * L2E;                    // pre-scaled for final exp2

    PIN(wir0); PIN(wir1); PIN(wiz0); PIN(wiz1); PIN(win0); PIN(win1);
#pragma unroll
    for (int k = 0; k < 8; ++k) { PIN(whr[k]); PIN(whz[k]); PIN(whn[k]); }
    PIN(br); PIN(bz); PIN(bn); PIN(wmx); PIN(wmy); PIN(bmv2);
    asm volatile("" ::: "memory");               // forbid re-loading from weight ptrs

    const f32x2* __restrict__ hp2  = (const f32x2*)hp;
    f32x2* __restrict__       out2 = (f32x2*)out;
    float* __restrict__       outo = out + ((long)nrows << 3);  // out scalars follow h_new

    // Branchless body: stores h_new pair, returns quad-reduced Dense(1) preact.
    auto body = [&](const f32x2 hv, const float g, const int p) -> float {
        // gradient preprocessing (per row, lane-redundant but instruction-free
        // at wave level). lg = log(|g|+eps)/10; branch continuous at lg==-1.
        const float ag = fabsf(g) + 1e-8f;
        const float lg = __builtin_amdgcn_logf(ag) * 0.069314718055994531f;
        const bool  hi = (lg >= -1.0f);
        f32x2 gin;
        gin.x = hi ? lg : -1.0f;
        gin.y = hi ? ((g > 0.0f) ? 1.0f : -1.0f)   // g != 0 guaranteed when hi
                   : 22026.465794806718f * g;      // exp(10) * g

        // broadcast the row's 8 h-values across the quad, pairwise (DPP):
        f32x2 hb0, hb1, hb2, hb3;
        hb0.x = QP(hv.x, QP_B0); hb0.y = QP(hv.y, QP_B0);
        hb1.x = QP(hv.x, QP_B1); hb1.y = QP(hv.y, QP_B1);
        hb2.x = QP(hv.x, QP_B2); hb2.y = QP(hv.y, QP_B2);
        hb3.x = QP(hv.x, QP_B3); hb3.y = QP(hv.y, QP_B3);

        f32x2 ar, az, an, hn;
        PK_FMA3_BLO(ar, wir0, gin, br);          // r/z pre-scaled by log2e
        PK_FMA_BHI (ar, wir1, gin);
        PK_FMA3_BLO(az, wiz0, gin, bz);
        PK_FMA_BHI (az, wiz1, gin);
        PK_MUL_BLO (an, win0, gin);              // input dense: no bias
        PK_FMA_BHI (an, win1, gin);
        PK_FMA3_BLO(hn, whn[0], hb0, bn);
        PK_FMA_BLO (ar, whr[0], hb0);
        PK_FMA_BLO (az, whz[0], hb0);
        PK_FMA_BHI (ar, whr[1], hb0);
        PK_FMA_BHI (az, whz[1], hb0);
        PK_FMA_BHI (hn, whn[1], hb0);
#define DOT2(Q, K0, K1) \
        PK_FMA_BLO(ar, whr[K0], hb##Q); \
        PK_FMA_BLO(az, whz[K0], hb##Q); \
        PK_FMA_BLO(hn, whn[K0], hb##Q); \
        PK_FMA_BHI(ar, whr[K1], hb##Q); \
        PK_FMA_BHI(az, whz[K1], hb##Q); \
        PK_FMA_BHI(hn, whn[K1], hb##Q);
        DOT2(1, 2, 3) DOT2(2, 4, 5) DOT2(3, 6, 7)
#undef DOT2

        // sigmoid with pre-scaled input: 1/(1+exp2(-x))  (no packed trans pipe)
        const float rx = __builtin_amdgcn_rcpf(1.0f + __builtin_amdgcn_exp2f(-ar.x));
        const float ry = __builtin_amdgcn_rcpf(1.0f + __builtin_amdgcn_exp2f(-ar.y));
        const float zx = __builtin_amdgcn_rcpf(1.0f + __builtin_amdgcn_exp2f(-az.x));
        const float zy = __builtin_amdgcn_rcpf(1.0f + __builtin_amdgcn_exp2f(-az.y));

        const float prex = fmaf(rx, hn.x, an.x);
        const float prey = fmaf(ry, hn.y, an.y);
        // overflow-safe tanh: t = exp2(-2*log2e*|x|) in [0,1]
        const float tx = __builtin_amdgcn_exp2f(-2.885390081777927f * fabsf(prex));
        const float ty = __builtin_amdgcn_exp2f(-2.885390081777927f * fabsf(prey));
        const float nx = copysignf((1.0f - tx) * __builtin_amdgcn_rcpf(1.0f + tx), prex);
        const float ny = copysignf((1.0f - ty) * __builtin_amdgcn_rcpf(1.0f + ty), prey);
        const float hnx = fmaf(zx, hv.x - nx, nx);   // (1-z)*n + z*h
        const float hny = fmaf(zy, hv.y - ny, ny);
        f32x2 ho; ho.x = hnx; ho.y = hny;
        out2[p] = ho;                            // coalesced dwordx2

        // Dense(1): reduce over the quad (DPP xor butterfly, stays on VALU)
        float s = fmaf(hny, wmy, hnx * wmx);
        s += QP(s, QP_X1);
        s += QP(s, QP_X2);
        return s;
    };

    auto finish = [&](const float s, const float g, const int p) {
        const float ov = -__builtin_amdgcn_exp2f(fmaf(s, L2E, bmv2)) * g;
        if (m == 0) outo[p >> 2] = ov;           // exec-masked store, no branch
    };

    const int stride2 = stride << 1;
    int pA = tid;
    if (pA < npairs) {
        int pB = pA + stride;
        const bool hasB = (pB < npairs);
        f32x2 hvA = hp2[pA];
        float gA  = gp[pA >> 2];
        f32x2 hvB = hvA;                         // init to avoid UB; overwritten
        float gB  = gA;
        if (hasB) { hvB = hp2[pB]; gB = gp[pB >> 2]; }

        int pA2 = pA + stride2, pB2 = pB + stride2;
        while (pB2 < npairs) {
            // prefetch the NEXT pair before computing the current one: the
            // ~1600cyc of two bodies hides the ~900cyc HBM latency in-wave.
            f32x2 hvA2 = hp2[pA2]; float gA2 = gp[pA2 >> 2];
            f32x2 hvB2 = hp2[pB2]; float gB2 = gp[pB2 >> 2];

            finish(body(hvA, gA, pA), gA, pA);
            finish(body(hvB, gB, pB), gB, pB);

            pA = pA2; pB = pB2;
            hvA = hvA2; gA = gA2;
            hvB = hvB2; gB = gB2;
            pA2 += stride2; pB2 += stride2;
        }
        // drain: A always valid+loaded; B if in range; at most one straggler.
        finish(body(hvA, gA, pA), gA, pA);
        if (pB < npairs) finish(body(hvB, gB, pB), gB, pB);
        if (pA2 < npairs) {
            const f32x2 hv = hp2[pA2];
            const float g  = gp[pA2 >> 2];
            finish(body(hv, g, pA2), g, pA2);
        }
    }
}

extern "C" void kernel_launch(void* const* d_in, const int* in_sizes, int n_in,
                              void* d_out, int out_size, void* d_ws, size_t ws_size,
                              hipStream_t stream) {
    const float* hp   = (const float*)d_in[0];
    const float* gp   = (const float*)d_in[1];
    const float* Wi_r = (const float*)d_in[2];
    const float* Wh_r = (const float*)d_in[3];
    const float* bh_r = (const float*)d_in[4];
    const float* Wi_z = (const float*)d_in[5];
    const float* Wh_z = (const float*)d_in[6];
    const float* bh_z = (const float*)d_in[7];
    const float* Wi_n = (const float*)d_in[8];
    const float* Wh_n = (const float*)d_in[9];
    const float* bh_n = (const float*)d_in[10];
    const float* Wm   = (const float*)d_in[11];
    const float* bm   = (const float*)d_in[12];
    const int nrows   = in_sizes[1];             // N = 8388608

    gru_l2l_kernel<<<8192, 256, 0, stream>>>(hp, gp, Wi_r, Wh_r, bh_r,
                                             Wi_z, Wh_z, bh_z,
                                             Wi_n, Wh_n, bh_n,
                                             Wm, bm, (float*)d_out, nrows);
}

// Round 5
// 541.959 us; speedup vs baseline: 1.0347x; 1.0347x over previous
//
#include <hip/hip_runtime.h>

// L2LGD2: learned-optimizer update step (GRUCell hid=8 + Dense(1) per row).
//
// R8: 8-lane-per-row, packed-over-ROWS layout.
// Post-mortem R3..R7: four structurally different kernels all ~195-210us.
// Diagnosis: VGPR_Count (28/48/60/56) was ALWAYS smaller than the pinned
// weight count (35/69/69/69) -> impossible without the allocator shuffling
// "pinned" values through AGPRs (gfx950 unified file; accvgpr moves are
// invisible to VGPR_Count and FETCH/WRITE but inflate VALUBusy ~2x vs static
// count and serialize every FMA chain). Root cause: 2 weight-columns/lane =
// 68 weight floats/lane can never be register-resident at a sane tier.
// Fix (structural): lane j owns ONE column j; each v_pk_fma_f32 packs TWO
// ROWS {2q, 2q+1} in .x/.y. Weights become scalars fed to both halves via
// op_sel on SRC0 -> 34 weight floats = 17 pair regs. Whole kernel ~90-100
// VGPRs, honestly resident.
//  - amdgpu_waves_per_eu(4,5): allocator budget <=128 (no squeeze-to-64+
//    spill), HW occupancy 5 waves/SIMD.
//  - h-broadcast via ds_swizzle 8-lane patterns (hardware-proven in R3);
//    LDS pipe overlaps VALU at 5 waves/SIMD.
//  - g loads: one dwordx2 {gA,gB}; outo stores: one dwordx2 per pair.
//  - grid 2048x256 -> 64 iterations/thread, weight preamble amortized;
//    1-deep prefetch.

typedef float f32x2 __attribute__((ext_vector_type(2)));

#define SWZ(x, imm) __int_as_float(__builtin_amdgcn_ds_swizzle(__float_as_int(x), (imm)))
#define PIN(x) asm volatile("" : "+v"(x))

// VOP3P f32 pairs; packed dim = rows {A,B}. Weight is a HALF of pair wp,
// broadcast to both result halves via op_sel/op_sel_hi on src0.
// d += w.lo * x   (x packed rows)
#define PK_FMA_WLO(d, wp, x) \
    asm("v_pk_fma_f32 %0, %1, %2, %0 op_sel:[0,0,0] op_sel_hi:[0,1,1]" \
        : "+v"(d) : "v"(wp), "v"(x))
// d += w.hi * x
#define PK_FMA_WHI(d, wp, x) \
    asm("v_pk_fma_f32 %0, %1, %2, %0 op_sel:[1,0,0] op_sel_hi:[1,1,1]" \
        : "+v"(d) : "v"(wp), "v"(x))
// d = w.lo * x + c.lo   (c.lo broadcast to both halves)
#define PK_FMA3_WLO_CLO(d, wp, x, cp) \
    asm("v_pk_fma_f32 %0, %1, %2, %3 op_sel:[0,0,0] op_sel_hi:[0,1,0]" \
        : "=v"(d) : "v"(wp), "v"(x), "v"(cp))
// d = w.lo * x + c.hi
#define PK_FMA3_WLO_CHI(d, wp, x, cp) \
    asm("v_pk_fma_f32 %0, %1, %2, %3 op_sel:[0,0,1] op_sel_hi:[0,1,1]" \
        : "=v"(d) : "v"(wp), "v"(x), "v"(cp))
// d = w.lo * x
#define PK_MUL_WLO(d, wp, x) \
    asm("v_pk_mul_f32 %0, %1, %2 op_sel:[0,0] op_sel_hi:[0,1]" \
        : "=v"(d) : "v"(wp), "v"(x))
// d = w.hi * x
#define PK_MUL_WHI(d, wp, x) \
    asm("v_pk_mul_f32 %0, %1, %2 op_sel:[1,0] op_sel_hi:[1,1]" \
        : "=v"(d) : "v"(wp), "v"(x))

__global__ __launch_bounds__(256) __attribute__((amdgpu_waves_per_eu(4, 5)))
void gru_l2l_kernel(
    const float* __restrict__ hp, const float* __restrict__ gp,
    const float* __restrict__ Wi_r, const float* __restrict__ Wh_r, const float* __restrict__ bh_r,
    const float* __restrict__ Wi_z, const float* __restrict__ Wh_z, const float* __restrict__ bh_z,
    const float* __restrict__ Wi_n, const float* __restrict__ Wh_n, const float* __restrict__ bh_n,
    const float* __restrict__ Wm, const float* __restrict__ bm,
    float* __restrict__ out, int nrows)
{
    const int NP    = nrows >> 1;                // row pairs
    const int tid   = blockIdx.x * blockDim.x + threadIdx.x;
    const int qstep = (blockDim.x * gridDim.x) >> 3;  // groups of 8 lanes
    const int j     = tid & 7;                   // hidden column owned

    const float L2E = 1.44269504088896341f;      // log2(e)

    // Per-lane weights: column j only -> 34 floats in 17 pair regs.
    // r/z weights+biases pre-scaled by log2e: sigmoid(x)=rcp(1+exp2(-x*log2e)).
    f32x2 wirp = { Wi_r[j] * L2E, Wi_r[8 + j] * L2E };   // {wir0, wir1}
    f32x2 wizp = { Wi_z[j] * L2E, Wi_z[8 + j] * L2E };
    f32x2 winp = { Wi_n[j],       Wi_n[8 + j] };
    f32x2 whrp[4], whzp[4], whnp[4];             // {Wh[2k][j], Wh[2k+1][j]}
#pragma unroll
    for (int k = 0; k < 4; ++k) {
        whrp[k] = (f32x2){ Wh_r[(2*k)*8 + j] * L2E, Wh_r[(2*k+1)*8 + j] * L2E };
        whzp[k] = (f32x2){ Wh_z[(2*k)*8 + j] * L2E, Wh_z[(2*k+1)*8 + j] * L2E };
        whnp[k] = (f32x2){ Wh_n[(2*k)*8 + j],       Wh_n[(2*k+1)*8 + j] };
    }
    f32x2 brzp  = { bh_r[j] * L2E, bh_z[j] * L2E };
    f32x2 bnwmp = { bh_n[j],       Wm[j] };
    float bmv2  = bm[0] * L2E;                   // pre-scaled for final exp2

    PIN(wirp); PIN(wizp); PIN(winp);
#pragma unroll
    for (int k = 0; k < 4; ++k) { PIN(whrp[k]); PIN(whzp[k]); PIN(whnp[k]); }
    PIN(brzp); PIN(bnwmp); PIN(bmv2);
    asm volatile("" ::: "memory");               // forbid re-loading from weight ptrs

    float* __restrict__ outo = out + ((long)nrows << 3);  // out scalars follow h_new

    // Packed body for rows {2q, 2q+1}: hvA/hvB = this lane's column of each.
    // dual=false (odd-row tail): only the A row is stored.
    auto doPair = [&](const int q, const f32x2 g2, const float hvA, const float hvB,
                      const bool dual) {
        const float gA = g2.x, gB = g2.y;
        // gradient preprocessing, both rows. lg=log(|g|+eps)/10; branch is
        // continuous at lg==-1 so fast-log flips are safe.
        const float agA = fabsf(gA) + 1e-8f;
        const float agB = fabsf(gB) + 1e-8f;
        const float lgA = __builtin_amdgcn_logf(agA) * 0.069314718055994531f;
        const float lgB = __builtin_amdgcn_logf(agB) * 0.069314718055994531f;
        const bool hiA = (lgA >= -1.0f), hiB = (lgB >= -1.0f);
        f32x2 gin0p, gin1p;
        gin0p.x = hiA ? lgA : -1.0f;
        gin0p.y = hiB ? lgB : -1.0f;
        gin1p.x = hiA ? ((gA > 0.0f) ? 1.0f : -1.0f) : 22026.465794806718f * gA;
        gin1p.y = hiB ? ((gB > 0.0f) ? 1.0f : -1.0f) : 22026.465794806718f * gB;

        // broadcast h[k] of both rows across the 8-lane group (R3-proven
        // BitMode patterns: src = (lane&0x18)|k -> offset=(k<<5)|0x18)
        f32x2 hb0, hb1, hb2, hb3, hb4, hb5, hb6, hb7;
        hb0.x = SWZ(hvA, 0x018); hb0.y = SWZ(hvB, 0x018);
        hb1.x = SWZ(hvA, 0x038); hb1.y = SWZ(hvB, 0x038);
        hb2.x = SWZ(hvA, 0x058); hb2.y = SWZ(hvB, 0x058);
        hb3.x = SWZ(hvA, 0x078); hb3.y = SWZ(hvB, 0x078);
        hb4.x = SWZ(hvA, 0x098); hb4.y = SWZ(hvB, 0x098);
        hb5.x = SWZ(hvA, 0x0B8); hb5.y = SWZ(hvB, 0x0B8);
        hb6.x = SWZ(hvA, 0x0D8); hb6.y = SWZ(hvB, 0x0D8);
        hb7.x = SWZ(hvA, 0x0F8); hb7.y = SWZ(hvB, 0x0F8);

        f32x2 ar2, az2, an2, hn2;
        PK_FMA3_WLO_CLO(ar2, wirp, gin0p, brzp);     // wir0*gin0 + br
        PK_FMA_WHI     (ar2, wirp, gin1p);           // + wir1*gin1
        PK_FMA3_WLO_CHI(az2, wizp, gin0p, brzp);     // wiz0*gin0 + bz
        PK_FMA_WHI     (az2, wizp, gin1p);
        PK_MUL_WLO     (an2, winp, gin0p);           // input dense: no bias
        PK_FMA_WHI     (an2, winp, gin1p);
        PK_FMA3_WLO_CLO(hn2, whnp[0], hb0, bnwmp);   // whn[0]*h0 + bn
        PK_FMA_WLO     (ar2, whrp[0], hb0);
        PK_FMA_WLO     (az2, whzp[0], hb0);
        PK_FMA_WHI     (ar2, whrp[0], hb1);
        PK_FMA_WHI     (az2, whzp[0], hb1);
        PK_FMA_WHI     (hn2, whnp[0], hb1);
#define DOTP(KP, QA, QB) \
        PK_FMA_WLO(ar2, whrp[KP], QA); \
        PK_FMA_WLO(az2, whzp[KP], QA); \
        PK_FMA_WLO(hn2, whnp[KP], QA); \
        PK_FMA_WHI(ar2, whrp[KP], QB); \
        PK_FMA_WHI(az2, whzp[KP], QB); \
        PK_FMA_WHI(hn2, whnp[KP], QB);
        DOTP(1, hb2, hb3) DOTP(2, hb4, hb5) DOTP(3, hb6, hb7)
#undef DOTP

        // sigmoid with pre-scaled input: 1/(1+exp2(-x))  (no packed trans)
        const float rA = __builtin_amdgcn_rcpf(1.0f + __builtin_amdgcn_exp2f(-ar2.x));
        const float rB = __builtin_amdgcn_rcpf(1.0f + __builtin_amdgcn_exp2f(-ar2.y));
        const float zA = __builtin_amdgcn_rcpf(1.0f + __builtin_amdgcn_exp2f(-az2.x));
        const float zB = __builtin_amdgcn_rcpf(1.0f + __builtin_amdgcn_exp2f(-az2.y));

        const float preA = fmaf(rA, hn2.x, an2.x);
        const float preB = fmaf(rB, hn2.y, an2.y);
        // overflow-safe tanh: t = exp2(-2*log2e*|x|) in [0,1]
        const float tA = __builtin_amdgcn_exp2f(-2.885390081777927f * fabsf(preA));
        const float tB = __builtin_amdgcn_exp2f(-2.885390081777927f * fabsf(preB));
        const float nA = copysignf((1.0f - tA) * __builtin_amdgcn_rcpf(1.0f + tA), preA);
        const float nB = copysignf((1.0f - tB) * __builtin_amdgcn_rcpf(1.0f + tB), preB);
        const float hnA = fmaf(zA, hvA - nA, nA);    // (1-z)*n + z*h
        const float hnB = fmaf(zB, hvB - nB, nB);

        out[(long)q * 16 + j] = hnA;                 // row A (32B/group dense)
        if (dual) out[(long)q * 16 + 8 + j] = hnB;   // row B

        // Dense(1): s = sum_j hnew[j]*Wm[j], packed butterfly over 8 lanes
        f32x2 hnew2; hnew2.x = hnA; hnew2.y = hnB;
        f32x2 s2; PK_MUL_WHI(s2, bnwmp, hnew2);      // * wm (hi of bnwmp)
        s2.x += SWZ(s2.x, 0x041F); s2.y += SWZ(s2.y, 0x041F);   // xor 1
        s2.x += SWZ(s2.x, 0x081F); s2.y += SWZ(s2.y, 0x081F);   // xor 2
        s2.x += SWZ(s2.x, 0x101F); s2.y += SWZ(s2.y, 0x101F);   // xor 4
        const float oA = -__builtin_amdgcn_exp2f(fmaf(s2.x, L2E, bmv2)) * gA;
        const float oB = -__builtin_amdgcn_exp2f(fmaf(s2.y, L2E, bmv2)) * gB;
        if (dual) {
            if (j == 0) {
                f32x2 o2; o2.x = oA; o2.y = oB;
                *reinterpret_cast<f32x2*>(outo + 2 * (long)q) = o2;
            }
        } else {
            if (j == 0) outo[2 * (long)q] = oA;
        }
    };

    // main loop: 1-deep prefetch; body runs only for q < NP (rotated form).
    int q = tid >> 3;
    if (q < NP) {
        f32x2 g2  = *reinterpret_cast<const f32x2*>(gp + 2 * (long)q);
        float hvA = hp[(long)q * 16 + j];
        float hvB = hp[(long)q * 16 + 8 + j];
        int qn = q + qstep;
        for (;;) {
            const bool more = (qn < NP);
            f32x2 g2n = g2; float hvAn = hvA, hvBn = hvB;
            if (more) {
                g2n  = *reinterpret_cast<const f32x2*>(gp + 2 * (long)qn);
                hvAn = hp[(long)qn * 16 + j];
                hvBn = hp[(long)qn * 16 + 8 + j];
            }
            doPair(q, g2, hvA, hvB, true);
            if (!more) break;
            q = qn; g2 = g2n; hvA = hvAn; hvB = hvBn;
            qn += qstep;
        }
    }

    // odd-row tail (absent for even N): duplicate the last row in both halves.
    if ((nrows & 1) && blockIdx.x == 0 && threadIdx.x < 8) {
        const long r = nrows - 1;
        const float g  = gp[r];
        const float hv = hp[r * 8 + j];
        f32x2 g2t; g2t.x = g; g2t.y = g;
        doPair((int)(r >> 1), g2t, hv, hv, false);
    }
}

extern "C" void kernel_launch(void* const* d_in, const int* in_sizes, int n_in,
                              void* d_out, int out_size, void* d_ws, size_t ws_size,
                              hipStream_t stream) {
    const float* hp   = (const float*)d_in[0];
    const float* gp   = (const float*)d_in[1];
    const float* Wi_r = (const float*)d_in[2];
    const float* Wh_r = (const float*)d_in[3];
    const float* bh_r = (const float*)d_in[4];
    const float* Wi_z = (const float*)d_in[5];
    const float* Wh_z = (const float*)d_in[6];
    const float* bh_z = (const float*)d_in[7];
    const float* Wi_n = (const float*)d_in[8];
    const float* Wh_n = (const float*)d_in[9];
    const float* bh_n = (const float*)d_in[10];
    const float* Wm   = (const float*)d_in[11];
    const float* bm   = (const float*)d_in[12];
    const int nrows   = in_sizes[1];             // N = 8388608

    gru_l2l_kernel<<<2048, 256, 0, stream>>>(hp, gp, Wi_r, Wh_r, bh_r,
                                             Wi_z, Wh_z, bh_z,
                                             Wi_n, Wh_n, bh_n,
                                             Wm, bm, (float*)d_out, nrows);
}

// Round 6
// 523.786 us; speedup vs baseline: 1.0706x; 1.0347x over previous
//
#include <hip/hip_runtime.h>

// L2LGD2: learned-optimizer update step (GRUCell hid=8 + Dense(1) per row).
//
// R9: plain-C++ rewrite + 4-deep memory pipeline.
// Plateau diagnosis (R3..R8, 192-210us for 5 structurally different kernels):
//  - VGPR_Count always << pinned-value count, even at (256,2) budget (R7: 56
//    granted vs 69 pinned) -> inline-asm pair constraints drive the allocator
//    into AGPR/scratch shuttling regardless of budget.
//  - Occupancy 41-43% with no visible limiter (VGPR ~50, LDS 0) -> hidden
//    scratch allocation capping waves = spills are real.
//  - fillBufferAligned in the same profile: 6.3 TB/s (79% peak) vs our 2.35
//    -> memory system fine; Little's law at ~3 outstanding loads/wave and
//    ~3.4-6.4 waves/SIMD predicts exactly ~2 TB/s. Latency-bound, MLP-starved.
// Fixes:
//  (a) NO inline-asm math. f32x2 + __builtin_elementwise_fma -> backend forms
//      v_pk_fma_f32 itself (worst case scalarizes = R3's proven 193us body).
//  (b) PIN only 35 SCALAR weights (one-shot opaque-value asm, prevents
//      rematerialization; no pair alignment, no memory clobber).
//  (c) __launch_bounds__(256,2): generous 256-reg budget, no squeeze.
//  (d) 4-deep software pipeline with named slots: 12 outstanding loads
//      (~2.3KB) per wave; at ~5 waves/SIMD -> ~11KB in flight/SIMD, which by
//      Little's law sustains >6 TB/s. Slot reload issued right after each
//      body's consumption (WAR -> compiler can hoist even earlier).
// Body math order identical to R3/R8 (same fmaf chains) -> absmax unchanged.

typedef float f32x2 __attribute__((ext_vector_type(2)));

#define SWZ(x, imm) __int_as_float(__builtin_amdgcn_ds_swizzle(__float_as_int(x), (imm)))
#define PIN(x) asm volatile("" : "+v"(x))

static __device__ __forceinline__ f32x2 splat2(float v) { f32x2 r; r.x = v; r.y = v; return r; }
static __device__ __forceinline__ f32x2 fma2(float w, f32x2 x, f32x2 a) {
    return __builtin_elementwise_fma(splat2(w), x, a);
}

__global__ __launch_bounds__(256, 2) void gru_l2l_kernel(
    const float* __restrict__ hp, const float* __restrict__ gp,
    const float* __restrict__ Wi_r, const float* __restrict__ Wh_r, const float* __restrict__ bh_r,
    const float* __restrict__ Wi_z, const float* __restrict__ Wh_z, const float* __restrict__ bh_z,
    const float* __restrict__ Wi_n, const float* __restrict__ Wh_n, const float* __restrict__ bh_n,
    const float* __restrict__ Wm, const float* __restrict__ bm,
    float* __restrict__ out, int nrows)
{
    const int NP  = nrows >> 1;                  // row pairs
    const int tid = blockIdx.x * blockDim.x + threadIdx.x;
    const int st  = (blockDim.x * gridDim.x) >> 3;   // total 8-lane groups
    const int g0  = tid >> 3;                    // this thread's group id
    const int j   = tid & 7;                     // hidden column owned

    const float L2E = 1.44269504088896341f;      // log2(e)

    // Per-lane weights: column j -> 35 scalars. r/z pre-scaled by log2e:
    // sigmoid(x) = rcp(1 + exp2(-x*log2e)).
    float wir0 = Wi_r[j] * L2E, wir1 = Wi_r[8 + j] * L2E;
    float wiz0 = Wi_z[j] * L2E, wiz1 = Wi_z[8 + j] * L2E;
    float win0 = Wi_n[j],       win1 = Wi_n[8 + j];
    float whr[8], whz[8], whn[8];
#pragma unroll
    for (int k = 0; k < 8; ++k) {
        whr[k] = Wh_r[k * 8 + j] * L2E;
        whz[k] = Wh_z[k * 8 + j] * L2E;
        whn[k] = Wh_n[k * 8 + j];
    }
    float br = bh_r[j] * L2E, bz = bh_z[j] * L2E, bn = bh_n[j];
    float wm = Wm[j];
    float bmv2 = bm[0] * L2E;                    // pre-scaled for final exp2

    // One-shot opaque-value pins: results become asm outputs, so they cannot
    // be rematerialized from memory inside the loop (volatile asm can't be
    // duplicated). Scalars only -> no pair-alignment fragmentation.
    PIN(wir0); PIN(wir1); PIN(wiz0); PIN(wiz1); PIN(win0); PIN(win1);
#pragma unroll
    for (int k = 0; k < 8; ++k) { PIN(whr[k]); PIN(whz[k]); PIN(whn[k]); }
    PIN(br); PIN(bz); PIN(bn); PIN(wm); PIN(bmv2);

    float* __restrict__ outo = out + ((long)nrows << 3);  // out scalars follow h_new

    // Body for rows {2q, 2q+1}: hvA/hvB = this lane's column of each row.
    auto doPair = [&](const float hvA, const float hvB, const f32x2 g2,
                      const int q, const bool dual) {
        const float gA = g2.x, gB = g2.y;
        // gradient preprocessing. lg = log(|g|+eps)/10; branch continuous at
        // lg==-1 so fast-log flips are safe.
        const float agA = fabsf(gA) + 1e-8f;
        const float agB = fabsf(gB) + 1e-8f;
        const float lgA = __builtin_amdgcn_logf(agA) * 0.069314718055994531f;
        const float lgB = __builtin_amdgcn_logf(agB) * 0.069314718055994531f;
        const bool hiA = (lgA >= -1.0f), hiB = (lgB >= -1.0f);
        f32x2 gi0, gi1;
        gi0.x = hiA ? lgA : -1.0f;
        gi0.y = hiB ? lgB : -1.0f;
        gi1.x = hiA ? ((gA > 0.0f) ? 1.0f : -1.0f) : 22026.465794806718f * gA;
        gi1.y = hiB ? ((gB > 0.0f) ? 1.0f : -1.0f) : 22026.465794806718f * gB;

        // broadcast h[k] of both rows across the 8-lane group (R3-proven
        // BitMode patterns: src = (lane&0x18)|k -> offset=(k<<5)|0x18)
        f32x2 hb0, hb1, hb2, hb3, hb4, hb5, hb6, hb7;
        hb0.x = SWZ(hvA, 0x018); hb0.y = SWZ(hvB, 0x018);
        hb1.x = SWZ(hvA, 0x038); hb1.y = SWZ(hvB, 0x038);
        hb2.x = SWZ(hvA, 0x058); hb2.y = SWZ(hvB, 0x058);
        hb3.x = SWZ(hvA, 0x078); hb3.y = SWZ(hvB, 0x078);
        hb4.x = SWZ(hvA, 0x098); hb4.y = SWZ(hvB, 0x098);
        hb5.x = SWZ(hvA, 0x0B8); hb5.y = SWZ(hvB, 0x0B8);
        hb6.x = SWZ(hvA, 0x0D8); hb6.y = SWZ(hvB, 0x0D8);
        hb7.x = SWZ(hvA, 0x0F8); hb7.y = SWZ(hvB, 0x0F8);

        f32x2 ar, az, an, hn;
        ar = fma2(wir1, gi1, fma2(wir0, gi0, splat2(br)));
        az = fma2(wiz1, gi1, fma2(wiz0, gi0, splat2(bz)));
        an = fma2(win1, gi1, splat2(win0) * gi0);    // input dense: no bias
        hn = splat2(bn);
#define DOTK(K, HB) \
        ar = fma2(whr[K], HB, ar); \
        az = fma2(whz[K], HB, az); \
        hn = fma2(whn[K], HB, hn);
        DOTK(0, hb0) DOTK(1, hb1) DOTK(2, hb2) DOTK(3, hb3)
        DOTK(4, hb4) DOTK(5, hb5) DOTK(6, hb6) DOTK(7, hb7)
#undef DOTK

        // sigmoid with pre-scaled input: 1/(1+exp2(-x))  (no packed trans)
        const float rA = __builtin_amdgcn_rcpf(1.0f + __builtin_amdgcn_exp2f(-ar.x));
        const float rB = __builtin_amdgcn_rcpf(1.0f + __builtin_amdgcn_exp2f(-ar.y));
        const float zA = __builtin_amdgcn_rcpf(1.0f + __builtin_amdgcn_exp2f(-az.x));
        const float zB = __builtin_amdgcn_rcpf(1.0f + __builtin_amdgcn_exp2f(-az.y));

        const float preA = fmaf(rA, hn.x, an.x);
        const float preB = fmaf(rB, hn.y, an.y);
        // overflow-safe tanh: t = exp2(-2*log2e*|x|) in [0,1]
        const float tA = __builtin_amdgcn_exp2f(-2.885390081777927f * fabsf(preA));
        const float tB = __builtin_amdgcn_exp2f(-2.885390081777927f * fabsf(preB));
        const float nA = copysignf((1.0f - tA) * __builtin_amdgcn_rcpf(1.0f + tA), preA);
        const float nB = copysignf((1.0f - tB) * __builtin_amdgcn_rcpf(1.0f + tB), preB);
        const float hnA = fmaf(zA, hvA - nA, nA);    // (1-z)*n + z*h
        const float hnB = fmaf(zB, hvB - nB, nB);

        out[(long)q * 16 + j] = hnA;                 // row A
        if (dual) out[(long)q * 16 + 8 + j] = hnB;   // row B

        // Dense(1): butterfly-reduce hnew*wm over the 8-lane group
        float sA = hnA * wm, sB = hnB * wm;
        sA += SWZ(sA, 0x041F); sB += SWZ(sB, 0x041F);   // xor 1
        sA += SWZ(sA, 0x081F); sB += SWZ(sB, 0x081F);   // xor 2
        sA += SWZ(sA, 0x101F); sB += SWZ(sB, 0x101F);   // xor 4
        const float oA = -__builtin_amdgcn_exp2f(fmaf(sA, L2E, bmv2)) * gA;
        const float oB = -__builtin_amdgcn_exp2f(fmaf(sB, L2E, bmv2)) * gB;
        if (dual) {
            if (j == 0) {
                f32x2 o2; o2.x = oA; o2.y = oB;
                *reinterpret_cast<f32x2*>(outo + 2 * (long)q) = o2;
            }
        } else {
            if (j == 0) outo[2 * (long)q] = oA;
        }
    };

    // 4-deep pipeline, named slots (no runtime-indexed arrays -> no scratch).
    float hA0, hA1, hA2, hA3, hB0, hB1, hB2, hB3;
    f32x2 gg0, gg1, gg2, gg3;
    const int NPm1 = NP - 1;
#define LOADS(S, Q) { int qq = (Q); qq = qq > NPm1 ? NPm1 : qq;           \
        const long b = (long)qq << 4;                                     \
        hA##S = hp[b + j]; hB##S = hp[b + 8 + j];                         \
        gg##S = *reinterpret_cast<const f32x2*>(gp + ((long)qq << 1)); }

    int qc = g0;
    if (qc < NP) {
        LOADS(0, qc) LOADS(1, qc + st) LOADS(2, qc + 2 * st) LOADS(3, qc + 3 * st)
        int qr = qc + 4 * st;
        while (qc + 3 * st < NP) {
            doPair(hA0, hB0, gg0, qc,          true);  LOADS(0, qr)
            doPair(hA1, hB1, gg1, qc + st,     true);  LOADS(1, qr + st)
            doPair(hA2, hB2, gg2, qc + 2 * st, true);  LOADS(2, qr + 2 * st)
            doPair(hA3, hB3, gg3, qc + 3 * st, true);  LOADS(3, qr + 3 * st)
            qc += st << 2; qr += st << 2;
        }
        if (qc < NP)          doPair(hA0, hB0, gg0, qc,          true);
        if (qc + st < NP)     doPair(hA1, hB1, gg1, qc + st,     true);
        if (qc + 2 * st < NP) doPair(hA2, hB2, gg2, qc + 2 * st, true);
    }
#undef LOADS

    // odd-row tail (absent for even N): single unpaired last row.
    if ((nrows & 1) && blockIdx.x == 0 && threadIdx.x < 8) {
        const long r = nrows - 1;
        const float g  = gp[r];
        const float hv = hp[r * 8 + j];
        f32x2 gt; gt.x = g; gt.y = g;
        doPair(hv, hv, gt, (int)(r >> 1), false);
    }
}

extern "C" void kernel_launch(void* const* d_in, const int* in_sizes, int n_in,
                              void* d_out, int out_size, void* d_ws, size_t ws_size,
                              hipStream_t stream) {
    const float* hp   = (const float*)d_in[0];
    const float* gp   = (const float*)d_in[1];
    const float* Wi_r = (const float*)d_in[2];
    const float* Wh_r = (const float*)d_in[3];
    const float* bh_r = (const float*)d_in[4];
    const float* Wi_z = (const float*)d_in[5];
    const float* Wh_z = (const float*)d_in[6];
    const float* bh_z = (const float*)d_in[7];
    const float* Wi_n = (const float*)d_in[8];
    const float* Wh_n = (const float*)d_in[9];
    const float* bh_n = (const float*)d_in[10];
    const float* Wm   = (const float*)d_in[11];
    const float* bm   = (const float*)d_in[12];
    const int nrows   = in_sizes[1];             // N = 8388608

    gru_l2l_kernel<<<2048, 256, 0, stream>>>(hp, gp, Wi_r, Wh_r, bh_r,
                                             Wi_z, Wh_z, bh_z,
                                             Wi_n, Wh_n, bh_n,
                                             Wm, bm, (float*)d_out, nrows);
}